// Round 7
// baseline (3252.591 us; speedup 1.0000x reference)
//
#include <hip/hip_runtime.h>
#include <stdint.h>
#include <stddef.h>

#define BATCH 128
#define NFRAMES 256
#define EMBED 768
#define RES 2048
#define NCLS 1000
#define NWG 128

typedef __attribute__((ext_vector_type(8))) short bf16x8;
typedef __attribute__((ext_vector_type(4))) float f32x4;
typedef unsigned short u16;

__device__ inline u16 f2bf(float f) {
    union { float f; unsigned u; } v; v.f = f;
    unsigned r = v.u + 0x7FFFu + ((v.u >> 16) & 1u);
    return (u16)(r >> 16);
}
__device__ inline float bf2f(u16 h) {
    union { unsigned u; float f; } v; v.u = ((unsigned)h) << 16;
    return v.f;
}

// ---------------- fp32 -> bf16 convert, vectorized x4 ----------------
__global__ __launch_bounds__(256) void cvt_kernel(const float* __restrict__ in,
                                                  u16* __restrict__ out, int n4) {
    int i = blockIdx.x * blockDim.x + threadIdx.x;
    int stride = gridDim.x * blockDim.x;
    for (; i < n4; i += stride) {
        float4 v = ((const float4*)in)[i];
        ushort4 o;
        o.x = f2bf(v.x); o.y = f2bf(v.y); o.z = f2bf(v.z); o.w = f2bf(v.w);
        ((ushort4*)out)[i] = o;
    }
}

// ---------------- projection: u[t,b,r] = sum_e x[b,t,e] * W_in[r,e] ----------------
__global__ __launch_bounds__(256) void proj_kernel(const u16* __restrict__ xb,
                                                   const u16* __restrict__ win,
                                                   u16* __restrict__ u) {
    int lane = threadIdx.x & 63;
    int w = threadIdx.x >> 6;
    int wm = w >> 1, wn = w & 1;
    int m0 = blockIdx.x * 128 + wm * 64;
    int n0 = blockIdx.y * 128 + wn * 64;
    int lr = lane & 15;
    int lk = (lane >> 4) * 8;

    f32x4 acc[4][4];
#pragma unroll
    for (int i = 0; i < 4; i++)
#pragma unroll
        for (int j = 0; j < 4; j++) acc[i][j] = (f32x4)0.f;

    for (int kk = 0; kk < EMBED; kk += 32) {
        bf16x8 a[4], b[4];
#pragma unroll
        for (int i = 0; i < 4; i++)
            a[i] = *(const bf16x8*)(xb + (size_t)(m0 + i * 16 + lr) * EMBED + kk + lk);
#pragma unroll
        for (int j = 0; j < 4; j++)
            b[j] = *(const bf16x8*)(win + (size_t)(n0 + j * 16 + lr) * EMBED + kk + lk);
#pragma unroll
        for (int i = 0; i < 4; i++)
#pragma unroll
            for (int j = 0; j < 4; j++)
                acc[i][j] = __builtin_amdgcn_mfma_f32_16x16x32_bf16(a[i], b[j], acc[i][j], 0, 0, 0);
    }

    int rowbase = (lane >> 4) * 4;
#pragma unroll
    for (int i = 0; i < 4; i++) {
#pragma unroll
        for (int j = 0; j < 4; j++) {
#pragma unroll
            for (int q = 0; q < 4; q++) {
                int m = m0 + i * 16 + rowbase + q;   // row index = b*NFRAMES + t
                int n = n0 + j * 16 + lr;            // reservoir index
                int bb = m >> 8, tt = m & 255;
                u[((size_t)tt * BATCH + bb) * RES + n] = f2bf(acc[i][j][q]);
            }
        }
    }
}

// ---------------- persistent recurrence, in-place state ring in u ----------------
// state[t] overwrites slot u[t] (u[t] dead after step t). Address freshness:
// before step t, lines of slot u[t] are cached only by their OWNER WG's XCD
// (uv read), and the owner's sc0sc1 write-through updates that copy. Remote
// XCDs cold-miss at t+1 and fetch fresh from IF. -> plain cached A-loads,
// NO fences, NO invalidation, full L1/L2 reuse.
// 128 WGs x 512 thr; half = blockIdx&1 (XCD-parity: all WGs of an XCD share
// the same 64 state rows); nblk = blockIdx>>1 (32 cols). 8 waves K-split 8x256.
__global__ __launch_bounds__(512, 1) void recur_kernel(const u16* __restrict__ res,
                                                       u16* __restrict__ u,
                                                       const u16* __restrict__ s0,
                                                       unsigned* __restrict__ flags) {
    __shared__ float part[8][64][34];
    const int lane = threadIdx.x & 63;
    const int w = threadIdx.x >> 6;          // K-slice 0..7
    const int half = (int)(blockIdx.x & 1);
    const int nblk = (int)(blockIdx.x >> 1);
    const int m0 = half * 64;
    const int n0 = nblk * 32;
    const int lr = lane & 15;
    const int lk = (lane >> 4) * 8;
    const int rb = (lane >> 4) * 4;
    const int kbase = w * 256;
    unsigned* myflag = flags + half * 64 + nblk;
    unsigned* pollflag = flags + half * 64 + lane;

    // persistent reservoir fragments (cached loads; immutable input)
    bf16x8 bfr[2][8];
#pragma unroll
    for (int jf = 0; jf < 2; jf++)
#pragma unroll
        for (int kk = 0; kk < 8; kk++)
            bfr[jf][kk] = *(const bf16x8*)(res + (size_t)(n0 + jf * 16 + lr) * RES + kbase + kk * 32 + lk);

    // epilogue indices: thread -> (row 0..63, col-quad 0..28)
    const int er = threadIdx.x >> 3;
    const int ec = (threadIdx.x & 7) * 4;
    const size_t gidx = (size_t)(m0 + er) * RES + n0 + ec;

    for (int t = 0; t < NFRAMES; t++) {
        const u16* sin = (t == 0) ? s0 : u + (size_t)(t - 1) * BATCH * RES;
        u16* sout = u + (size_t)t * BATCH * RES;

        // u-value read (own elements of slot t, before overwrite; cached)
        uint2 uv = *(const uint2*)(sout + gidx);

        f32x4 acc[4][2];
#pragma unroll
        for (int i = 0; i < 4; i++) { acc[i][0] = (f32x4)0.f; acc[i][1] = (f32x4)0.f; }

#pragma unroll
        for (int i = 0; i < 4; i++) {
            const u16* ap = sin + (size_t)(m0 + i * 16 + lr) * RES + kbase + lk;
            bf16x8 a[8];
#pragma unroll
            for (int kk = 0; kk < 8; kk++)
                a[kk] = *(const bf16x8*)(ap + kk * 32);
#pragma unroll
            for (int kk = 0; kk < 8; kk++) {
                acc[i][0] = __builtin_amdgcn_mfma_f32_16x16x32_bf16(a[kk], bfr[0][kk], acc[i][0], 0, 0, 0);
                acc[i][1] = __builtin_amdgcn_mfma_f32_16x16x32_bf16(a[kk], bfr[1][kk], acc[i][1], 0, 0, 0);
            }
        }

        // K-partials -> LDS (pad 34: 2-way bank aliasing only, free)
#pragma unroll
        for (int i = 0; i < 4; i++)
#pragma unroll
            for (int jf = 0; jf < 2; jf++)
#pragma unroll
                for (int q = 0; q < 4; q++)
                    part[w][i * 16 + rb + q][jf * 16 + lr] = acc[i][jf][q];
        __syncthreads();

        // single-pass reduce over 8 waves + u add + tanh + packed write-through store
        float sum0 = 0.f, sum1 = 0.f, sum2 = 0.f, sum3 = 0.f;
#pragma unroll
        for (int ww = 0; ww < 8; ww++) {
            const float* pr = &part[ww][er][ec];
            float2 v01 = *(const float2*)pr;
            float2 v23 = *(const float2*)(pr + 2);
            sum0 += v01.x; sum1 += v01.y; sum2 += v23.x; sum3 += v23.y;
        }
        float v0 = tanhf(sum0 + bf2f((u16)(uv.x & 0xFFFF)));
        float v1 = tanhf(sum1 + bf2f((u16)(uv.x >> 16)));
        float v2 = tanhf(sum2 + bf2f((u16)(uv.y & 0xFFFF)));
        float v3 = tanhf(sum3 + bf2f((u16)(uv.y >> 16)));
        uint2 pk;
        pk.x = (unsigned)f2bf(v0) | ((unsigned)f2bf(v1) << 16);
        pk.y = (unsigned)f2bf(v2) | ((unsigned)f2bf(v3) << 16);
        asm volatile("global_store_dwordx2 %0, %1, off sc0 sc1"
                     :: "v"(sout + gidx), "v"(pk) : "memory");

        // drain own stores (write-through -> visible at IF, local L2 updated),
        // then half-scoped flag barrier: own-slot stamp + 64-lane parallel poll.
        asm volatile("s_waitcnt vmcnt(0)" ::: "memory");
        __syncthreads();
        if (t != NFRAMES - 1) {
            if (w == 0) {
                if (lane == 0)
                    __hip_atomic_store(myflag, (unsigned)(t + 1), __ATOMIC_RELAXED,
                                       __HIP_MEMORY_SCOPE_SYSTEM);
                unsigned f;
                do {
                    f = __hip_atomic_load(pollflag, __ATOMIC_RELAXED,
                                          __HIP_MEMORY_SCOPE_SYSTEM);
                    if (__all((int)(f >= (unsigned)(t + 1)))) break;
                    __builtin_amdgcn_s_sleep(1);
                } while (1);
            }
            __syncthreads();
        }
    }
}

// ---------------- head: logits[b,c] = sum_r s[b,r]*W_out[c,r] + bias[c] ----------------
__global__ __launch_bounds__(512) void head_kernel(const u16* __restrict__ sin,
                                                   const u16* __restrict__ wout,
                                                   const float* __restrict__ bias,
                                                   float* __restrict__ out) {
    __shared__ float part[8][32][33];
    int lane = threadIdx.x & 63;
    int w = threadIdx.x >> 6;
    int m0 = blockIdx.x * 32;
    int n0 = blockIdx.y * 32;   // over padded 1024
    int k0 = w * 256;
    int lr = lane & 15;
    int lk = (lane >> 4) * 8;

    f32x4 acc[2][2];
#pragma unroll
    for (int i = 0; i < 2; i++)
#pragma unroll
        for (int j = 0; j < 2; j++) acc[i][j] = (f32x4)0.f;

    for (int kk = k0; kk < k0 + 256; kk += 32) {
        bf16x8 a[2], b[2];
#pragma unroll
        for (int i = 0; i < 2; i++)
            a[i] = *(const bf16x8*)(sin + (size_t)(m0 + i * 16 + lr) * RES + kk + lk);
#pragma unroll
        for (int j = 0; j < 2; j++) {
            int row = n0 + j * 16 + lr;
            if (row > NCLS - 1) row = NCLS - 1;  // clamp, result unused
            b[j] = *(const bf16x8*)(wout + (size_t)row * RES + kk + lk);
        }
#pragma unroll
        for (int i = 0; i < 2; i++)
#pragma unroll
            for (int j = 0; j < 2; j++)
                acc[i][j] = __builtin_amdgcn_mfma_f32_16x16x32_bf16(a[i], b[j], acc[i][j], 0, 0, 0);
    }

    int rowbase = (lane >> 4) * 4;
#pragma unroll
    for (int i = 0; i < 2; i++)
#pragma unroll
        for (int j = 0; j < 2; j++)
#pragma unroll
            for (int q = 0; q < 4; q++)
                part[w][i * 16 + rowbase + q][j * 16 + lr] = acc[i][j][q];

    __syncthreads();

    for (int idx = threadIdx.x; idx < 1024; idx += 512) {
        int r = idx >> 5, c = idx & 31;
        float s = 0.f;
#pragma unroll
        for (int ww = 0; ww < 8; ww++) s += part[ww][r][c];
        int cg = n0 + c;
        if (cg < NCLS)
            out[(size_t)(m0 + r) * NCLS + cg] = s + bias[cg];
    }
}

extern "C" void kernel_launch(void* const* d_in, const int* in_sizes, int n_in,
                              void* d_out, int out_size, void* d_ws, size_t ws_size,
                              hipStream_t stream) {
    const float* x_f    = (const float*)d_in[0];  // [128,256,768]
    const float* res_f  = (const float*)d_in[1];  // [2048,2048]
    const float* win_f  = (const float*)d_in[2];  // [2048,768]
    const float* wout_f = (const float*)d_in[3];  // [1000,2048]
    const float* bias   = (const float*)d_in[4];  // [1000]
    float* out = (float*)d_out;

    char* ws = (char*)d_ws;
    size_t off = 0;
    auto alloc = [&](size_t bytes) -> void* {
        void* p = ws + off;
        off += (bytes + 255) & ~(size_t)255;
        return p;
    };
    u16* res_b  = (u16*)alloc((size_t)RES * RES * 2);
    u16* win_b  = (u16*)alloc((size_t)RES * EMBED * 2);
    u16* wout_b = (u16*)alloc((size_t)NCLS * RES * 2);
    u16* x_b    = (u16*)alloc((size_t)BATCH * NFRAMES * EMBED * 2);
    u16* u      = (u16*)alloc((size_t)NFRAMES * BATCH * RES * 2);  // u / state ring (in-place)
    u16* s0     = (u16*)alloc((size_t)BATCH * RES * 2);            // zero initial state
    unsigned* flags = (unsigned*)alloc(1024);

    // weight / input conversion to bf16
    cvt_kernel<<<dim3(1024), dim3(256), 0, stream>>>(res_f, res_b, RES * RES / 4);
    cvt_kernel<<<dim3(512), dim3(256), 0, stream>>>(win_f, win_b, RES * EMBED / 4);
    cvt_kernel<<<dim3(512), dim3(256), 0, stream>>>(wout_f, wout_b, NCLS * RES / 4);
    cvt_kernel<<<dim3(2048), dim3(256), 0, stream>>>(x_f, x_b, BATCH * NFRAMES * EMBED / 4);

    // state0 = 0, flags = 0 (ws poisoned 0xAA; re-init every call)
    hipMemsetAsync(s0, 0, (size_t)BATCH * RES * 2, stream);
    hipMemsetAsync(flags, 0, 1024, stream);

    // u[t,b,r] projection GEMM
    proj_kernel<<<dim3(256, 16), dim3(256), 0, stream>>>(x_b, win_b, u);

    // all 256 recurrence steps in one cooperative launch; state[t] -> slot u[t]
    void* args[] = { (void*)&res_b, (void*)&u, (void*)&s0, (void*)&flags };
    hipLaunchCooperativeKernel((const void*)recur_kernel, dim3(NWG), dim3(512),
                               args, 0, stream);

    // final state lives in slot u[255]
    const u16* sfin = u + (size_t)(NFRAMES - 1) * BATCH * RES;
    void* hs = (void*)sfin;
    head_kernel<<<dim3(4, 32), dim3(512), 0, stream>>>((const u16*)hs, wout_b, bias, out);
}

// Round 9
// 2591.754 us; speedup vs baseline: 1.2550x; 1.2550x over previous
//
#include <hip/hip_runtime.h>
#include <stdint.h>
#include <stddef.h>

#define BATCH 128
#define NFRAMES 256
#define EMBED 768
#define RES 2048
#define NCLS 1000
#define NWG 128

typedef __attribute__((ext_vector_type(8))) short bf16x8;
typedef __attribute__((ext_vector_type(4))) float f32x4;
typedef unsigned short u16;

__device__ inline u16 f2bf(float f) {
    union { float f; unsigned u; } v; v.f = f;
    unsigned r = v.u + 0x7FFFu + ((v.u >> 16) & 1u);
    return (u16)(r >> 16);
}
__device__ inline float bf2f(u16 h) {
    union { unsigned u; float f; } v; v.u = ((unsigned)h) << 16;
    return v.f;
}

// ---------------- fp32 -> bf16 convert, vectorized x4 ----------------
__global__ __launch_bounds__(256) void cvt_kernel(const float* __restrict__ in,
                                                  u16* __restrict__ out, int n4) {
    int i = blockIdx.x * blockDim.x + threadIdx.x;
    int stride = gridDim.x * blockDim.x;
    for (; i < n4; i += stride) {
        float4 v = ((const float4*)in)[i];
        ushort4 o;
        o.x = f2bf(v.x); o.y = f2bf(v.y); o.z = f2bf(v.z); o.w = f2bf(v.w);
        ((ushort4*)out)[i] = o;
    }
}

// ---------------- projection: u[t,b,r] = sum_e x[b,t,e] * W_in[r,e] ----------------
__global__ __launch_bounds__(256) void proj_kernel(const u16* __restrict__ xb,
                                                   const u16* __restrict__ win,
                                                   u16* __restrict__ u) {
    int lane = threadIdx.x & 63;
    int w = threadIdx.x >> 6;
    int wm = w >> 1, wn = w & 1;
    int m0 = blockIdx.x * 128 + wm * 64;
    int n0 = blockIdx.y * 128 + wn * 64;
    int lr = lane & 15;
    int lk = (lane >> 4) * 8;

    f32x4 acc[4][4];
#pragma unroll
    for (int i = 0; i < 4; i++)
#pragma unroll
        for (int j = 0; j < 4; j++) acc[i][j] = (f32x4)0.f;

    for (int kk = 0; kk < EMBED; kk += 32) {
        bf16x8 a[4], b[4];
#pragma unroll
        for (int i = 0; i < 4; i++)
            a[i] = *(const bf16x8*)(xb + (size_t)(m0 + i * 16 + lr) * EMBED + kk + lk);
#pragma unroll
        for (int j = 0; j < 4; j++)
            b[j] = *(const bf16x8*)(win + (size_t)(n0 + j * 16 + lr) * EMBED + kk + lk);
#pragma unroll
        for (int i = 0; i < 4; i++)
#pragma unroll
            for (int j = 0; j < 4; j++)
                acc[i][j] = __builtin_amdgcn_mfma_f32_16x16x32_bf16(a[i], b[j], acc[i][j], 0, 0, 0);
    }

    int rowbase = (lane >> 4) * 4;
#pragma unroll
    for (int i = 0; i < 4; i++) {
#pragma unroll
        for (int j = 0; j < 4; j++) {
#pragma unroll
            for (int q = 0; q < 4; q++) {
                int m = m0 + i * 16 + rowbase + q;   // row index = b*NFRAMES + t
                int n = n0 + j * 16 + lr;            // reservoir index
                int bb = m >> 8, tt = m & 255;
                u[((size_t)tt * BATCH + bb) * RES + n] = f2bf(acc[i][j][q]);
            }
        }
    }
}

// ---------------- persistent recurrence ----------------
// 128 WGs x 512 thr. WG tile: 32 rows x 64 cols (rowblk = blockIdx&3,
// colblk = blockIdx>>2). 8 waves K-split 8x256. B: 4 col-frags x 8 K-subs
// persistent in VGPRs (128). A: 16 uncached wide loads issued upfront,
// counted vmcnt between the two row-frag MFMA blocks.
// State exchange: sc0sc1 write-through stores + uncached loads (IF-coherent,
// no fences). Barrier: per-WG stamp flag + single dwordx4 wave-poll
// (32 lanes cover 128 flags) with s_sleep(4) -> ~30x less poll traffic.
__global__ __launch_bounds__(512, 2) void recur_kernel(const u16* __restrict__ res,
                                                       const u16* __restrict__ u,
                                                       u16* __restrict__ s0,
                                                       u16* __restrict__ s1,
                                                       unsigned* __restrict__ flags) {
    __shared__ float part[8][32][66];
    const int lane = threadIdx.x & 63;
    const int w = threadIdx.x >> 6;          // K-slice 0..7
    const int m0 = (int)(blockIdx.x & 3) * 32;
    const int n0 = (int)(blockIdx.x >> 2) * 64;
    const int lr = lane & 15;
    const int lk = (lane >> 4) * 8;
    const int rb = (lane >> 4) * 4;
    const int kbase = w * 256;
    unsigned* myflag = flags + blockIdx.x;

    // persistent reservoir B-fragments: 4 col-frags x 8 K-subs = 128 VGPR/lane
    bf16x8 bfr[4][8];
#pragma unroll
    for (int jf = 0; jf < 4; jf++)
#pragma unroll
        for (int kk = 0; kk < 8; kk++)
            bfr[jf][kk] = *(const bf16x8*)(res + (size_t)(n0 + jf * 16 + lr) * RES + kbase + kk * 32 + lk);

    // epilogue mapping: thread -> (row 0..31, col-quad)
    const int er = threadIdx.x >> 4;          // 0..31
    const int ec = (threadIdx.x & 15) * 4;    // 0..60
    const size_t gidx = (size_t)(m0 + er) * RES + n0 + ec;

    for (int t = 0; t < NFRAMES; t++) {
        const u16* sin = (t & 1) ? s1 : s0;
        u16* sout = (t & 1) ? s0 : s1;
        const u16* abase = sin + (size_t)(m0 + lr) * RES + kbase + lk;

        // u prefetch (immutable input, cached)
        uint2 uv = *(const uint2*)(u + (size_t)t * BATCH * RES + gidx);

        // issue ALL 16 A-loads upfront (2 row-frags x 8 K-subs, uncached wide)
        bf16x8 a0[8], a1[8];
#pragma unroll
        for (int kk = 0; kk < 8; kk++)
            asm volatile("global_load_dwordx4 %0, %1, off sc0 sc1"
                         : "=v"(a0[kk]) : "v"(abase + kk * 32));
        const u16* abase1 = abase + (size_t)16 * RES;
#pragma unroll
        for (int kk = 0; kk < 8; kk++)
            asm volatile("global_load_dwordx4 %0, %1, off sc0 sc1"
                         : "=v"(a1[kk]) : "v"(abase1 + kk * 32));

        f32x4 acc0[4], acc1[4];
#pragma unroll
        for (int jf = 0; jf < 4; jf++) { acc0[jf] = (f32x4)0.f; acc1[jf] = (f32x4)0.f; }

        asm volatile("s_waitcnt vmcnt(8)" ::: "memory");
        __builtin_amdgcn_sched_barrier(0);
#pragma unroll
        for (int kk = 0; kk < 8; kk++)
#pragma unroll
            for (int jf = 0; jf < 4; jf++)
                acc0[jf] = __builtin_amdgcn_mfma_f32_16x16x32_bf16(a0[kk], bfr[jf][kk], acc0[jf], 0, 0, 0);
        asm volatile("s_waitcnt vmcnt(0)" ::: "memory");
        __builtin_amdgcn_sched_barrier(0);
#pragma unroll
        for (int kk = 0; kk < 8; kk++)
#pragma unroll
            for (int jf = 0; jf < 4; jf++)
                acc1[jf] = __builtin_amdgcn_mfma_f32_16x16x32_bf16(a1[kk], bfr[jf][kk], acc1[jf], 0, 0, 0);

        // K-partials -> LDS
#pragma unroll
        for (int jf = 0; jf < 4; jf++)
#pragma unroll
            for (int q = 0; q < 4; q++) {
                part[w][rb + q][jf * 16 + lr]      = acc0[jf][q];
                part[w][16 + rb + q][jf * 16 + lr] = acc1[jf][q];
            }
        __syncthreads();

        // reduce 8 K-partials + u add + tanh + packed write-through store
        float s0v = 0.f, s1v = 0.f, s2v = 0.f, s3v = 0.f;
#pragma unroll
        for (int ww = 0; ww < 8; ww++) {
            const float* pr = &part[ww][er][ec];
            float2 v01 = *(const float2*)pr;
            float2 v23 = *(const float2*)(pr + 2);
            s0v += v01.x; s1v += v01.y; s2v += v23.x; s3v += v23.y;
        }
        float v0 = tanhf(s0v + bf2f((u16)(uv.x & 0xFFFF)));
        float v1 = tanhf(s1v + bf2f((u16)(uv.x >> 16)));
        float v2 = tanhf(s2v + bf2f((u16)(uv.y & 0xFFFF)));
        float v3 = tanhf(s3v + bf2f((u16)(uv.y >> 16)));
        uint2 pk;
        pk.x = (unsigned)f2bf(v0) | ((unsigned)f2bf(v1) << 16);
        pk.y = (unsigned)f2bf(v2) | ((unsigned)f2bf(v3) << 16);
        asm volatile("global_store_dwordx2 %0, %1, off sc0 sc1"
                     :: "v"(sout + gidx), "v"(pk) : "memory");

        // drain own stores, then low-traffic flag barrier
        asm volatile("s_waitcnt vmcnt(0)" ::: "memory");
        __syncthreads();
        if (t != NFRAMES - 1) {
            unsigned stamp = (unsigned)(t + 1);
            if (w == 0) {
                if (lane == 0)
                    asm volatile("global_store_dword %0, %1, off sc0 sc1"
                                 :: "v"(myflag), "v"(stamp) : "memory");
                if (lane < 32) {
                    const unsigned* pf = flags + lane * 4;
                    do {
                        uint4 f;
                        asm volatile("global_load_dwordx4 %0, %1, off sc0 sc1\n\ts_waitcnt vmcnt(0)"
                                     : "=v"(f) : "v"(pf) : "memory");
                        unsigned mn = min(min(f.x, f.y), min(f.z, f.w));
                        if (__all((int)(mn >= stamp))) break;
                        __builtin_amdgcn_s_sleep(4);
                    } while (1);
                }
            }
            __syncthreads();
        }
    }
}

// ---------------- head: logits[b,c] = sum_r s[b,r]*W_out[c,r] + bias[c] ----------------
__global__ __launch_bounds__(512) void head_kernel(const u16* __restrict__ sin,
                                                   const u16* __restrict__ wout,
                                                   const float* __restrict__ bias,
                                                   float* __restrict__ out) {
    __shared__ float part[8][32][33];
    int lane = threadIdx.x & 63;
    int w = threadIdx.x >> 6;
    int m0 = blockIdx.x * 32;
    int n0 = blockIdx.y * 32;   // over padded 1024
    int k0 = w * 256;
    int lr = lane & 15;
    int lk = (lane >> 4) * 8;

    f32x4 acc[2][2];
#pragma unroll
    for (int i = 0; i < 2; i++)
#pragma unroll
        for (int j = 0; j < 2; j++) acc[i][j] = (f32x4)0.f;

    for (int kk = k0; kk < k0 + 256; kk += 32) {
        bf16x8 a[2], b[2];
#pragma unroll
        for (int i = 0; i < 2; i++)
            a[i] = *(const bf16x8*)(sin + (size_t)(m0 + i * 16 + lr) * RES + kk + lk);
#pragma unroll
        for (int j = 0; j < 2; j++) {
            int row = n0 + j * 16 + lr;
            if (row > NCLS - 1) row = NCLS - 1;  // clamp, result unused
            b[j] = *(const bf16x8*)(wout + (size_t)row * RES + kk + lk);
        }
#pragma unroll
        for (int i = 0; i < 2; i++)
#pragma unroll
            for (int j = 0; j < 2; j++)
                acc[i][j] = __builtin_amdgcn_mfma_f32_16x16x32_bf16(a[i], b[j], acc[i][j], 0, 0, 0);
    }

    int rowbase = (lane >> 4) * 4;
#pragma unroll
    for (int i = 0; i < 2; i++)
#pragma unroll
        for (int j = 0; j < 2; j++)
#pragma unroll
            for (int q = 0; q < 4; q++)
                part[w][i * 16 + rowbase + q][j * 16 + lr] = acc[i][j][q];

    __syncthreads();

    for (int idx = threadIdx.x; idx < 1024; idx += 512) {
        int r = idx >> 5, c = idx & 31;
        float s = 0.f;
#pragma unroll
        for (int ww = 0; ww < 8; ww++) s += part[ww][r][c];
        int cg = n0 + c;
        if (cg < NCLS)
            out[(size_t)(m0 + r) * NCLS + cg] = s + bias[cg];
    }
}

extern "C" void kernel_launch(void* const* d_in, const int* in_sizes, int n_in,
                              void* d_out, int out_size, void* d_ws, size_t ws_size,
                              hipStream_t stream) {
    const float* x_f    = (const float*)d_in[0];  // [128,256,768]
    const float* res_f  = (const float*)d_in[1];  // [2048,2048]
    const float* win_f  = (const float*)d_in[2];  // [2048,768]
    const float* wout_f = (const float*)d_in[3];  // [1000,2048]
    const float* bias   = (const float*)d_in[4];  // [1000]
    float* out = (float*)d_out;

    char* ws = (char*)d_ws;
    size_t off = 0;
    auto alloc = [&](size_t bytes) -> void* {
        void* p = ws + off;
        off += (bytes + 255) & ~(size_t)255;
        return p;
    };
    u16* res_b  = (u16*)alloc((size_t)RES * RES * 2);
    u16* win_b  = (u16*)alloc((size_t)RES * EMBED * 2);
    u16* wout_b = (u16*)alloc((size_t)NCLS * RES * 2);
    u16* x_b    = (u16*)alloc((size_t)BATCH * NFRAMES * EMBED * 2);
    u16* u      = (u16*)alloc((size_t)NFRAMES * BATCH * RES * 2);
    u16* s0     = (u16*)alloc((size_t)BATCH * RES * 2);
    u16* s1     = (u16*)alloc((size_t)BATCH * RES * 2);
    unsigned* flags = (unsigned*)alloc(1024);

    // weight / input conversion to bf16
    cvt_kernel<<<dim3(1024), dim3(256), 0, stream>>>(res_f, res_b, RES * RES / 4);
    cvt_kernel<<<dim3(512), dim3(256), 0, stream>>>(win_f, win_b, RES * EMBED / 4);
    cvt_kernel<<<dim3(512), dim3(256), 0, stream>>>(wout_f, wout_b, NCLS * RES / 4);
    cvt_kernel<<<dim3(2048), dim3(256), 0, stream>>>(x_f, x_b, BATCH * NFRAMES * EMBED / 4);

    // state0 = 0, flags = 0 (ws poisoned 0xAA; re-init every call)
    hipMemsetAsync(s0, 0, (size_t)BATCH * RES * 2, stream);
    hipMemsetAsync(flags, 0, 1024, stream);

    // u[t,b,r] projection GEMM
    proj_kernel<<<dim3(256, 16), dim3(256), 0, stream>>>(x_b, win_b, u);

    // all 256 recurrence steps in one cooperative launch
    void* args[] = { (void*)&res_b, (void*)&u, (void*)&s0, (void*)&s1, (void*)&flags };
    hipLaunchCooperativeKernel((const void*)recur_kernel, dim3(NWG), dim3(512),
                               args, 0, stream);

    // final state is in s0 (t=255 odd -> wrote s0)
    head_kernel<<<dim3(4, 32), dim3(512), 0, stream>>>(s0, wout_b, bias, out);
}

// Round 10
// 1415.165 us; speedup vs baseline: 2.2984x; 1.8314x over previous
//
#include <hip/hip_runtime.h>
#include <stdint.h>
#include <stddef.h>

#define BATCH 128
#define NFRAMES 256
#define EMBED 768
#define RES 2048
#define NCLS 1000
#define NWG 256

typedef __attribute__((ext_vector_type(8))) short bf16x8;
typedef __attribute__((ext_vector_type(4))) float f32x4;
typedef unsigned short u16;

__device__ inline u16 f2bf(float f) {
    union { float f; unsigned u; } v; v.f = f;
    unsigned r = v.u + 0x7FFFu + ((v.u >> 16) & 1u);
    return (u16)(r >> 16);
}
__device__ inline float bf2f(u16 h) {
    union { unsigned u; float f; } v; v.u = ((unsigned)h) << 16;
    return v.f;
}
// tanh(x) = 1 - 2/(e^{2x}+1), via HW exp2 + rcp (4 VALU ops, saturates correctly)
__device__ inline float tanh_fast(float x) {
    float z = __builtin_amdgcn_exp2f(x * 2.885390081777927f);  // e^{2x}
    return 1.f - 2.f * __builtin_amdgcn_rcpf(z + 1.f);
}

// ---------------- fp32 -> bf16 convert, vectorized x4 ----------------
__global__ __launch_bounds__(256) void cvt_kernel(const float* __restrict__ in,
                                                  u16* __restrict__ out, int n4) {
    int i = blockIdx.x * blockDim.x + threadIdx.x;
    int stride = gridDim.x * blockDim.x;
    for (; i < n4; i += stride) {
        float4 v = ((const float4*)in)[i];
        ushort4 o;
        o.x = f2bf(v.x); o.y = f2bf(v.y); o.z = f2bf(v.z); o.w = f2bf(v.w);
        ((ushort4*)out)[i] = o;
    }
}

// ---------------- projection: u[t,b,r] = sum_e x[b,t,e] * W_in[r,e] ----------------
__global__ __launch_bounds__(256) void proj_kernel(const u16* __restrict__ xb,
                                                   const u16* __restrict__ win,
                                                   u16* __restrict__ u) {
    int lane = threadIdx.x & 63;
    int w = threadIdx.x >> 6;
    int wm = w >> 1, wn = w & 1;
    int m0 = blockIdx.x * 128 + wm * 64;
    int n0 = blockIdx.y * 128 + wn * 64;
    int lr = lane & 15;
    int lk = (lane >> 4) * 8;

    f32x4 acc[4][4];
#pragma unroll
    for (int i = 0; i < 4; i++)
#pragma unroll
        for (int j = 0; j < 4; j++) acc[i][j] = (f32x4)0.f;

    for (int kk = 0; kk < EMBED; kk += 32) {
        bf16x8 a[4], b[4];
#pragma unroll
        for (int i = 0; i < 4; i++)
            a[i] = *(const bf16x8*)(xb + (size_t)(m0 + i * 16 + lr) * EMBED + kk + lk);
#pragma unroll
        for (int j = 0; j < 4; j++)
            b[j] = *(const bf16x8*)(win + (size_t)(n0 + j * 16 + lr) * EMBED + kk + lk);
#pragma unroll
        for (int i = 0; i < 4; i++)
#pragma unroll
            for (int j = 0; j < 4; j++)
                acc[i][j] = __builtin_amdgcn_mfma_f32_16x16x32_bf16(a[i], b[j], acc[i][j], 0, 0, 0);
    }

    int rowbase = (lane >> 4) * 4;
#pragma unroll
    for (int i = 0; i < 4; i++) {
#pragma unroll
        for (int j = 0; j < 4; j++) {
#pragma unroll
            for (int q = 0; q < 4; q++) {
                int m = m0 + i * 16 + rowbase + q;   // row index = b*NFRAMES + t
                int n = n0 + j * 16 + lr;            // reservoir index
                int bb = m >> 8, tt = m & 255;
                u[((size_t)tt * BATCH + bb) * RES + n] = f2bf(acc[i][j][q]);
            }
        }
    }
}

// ---------------- persistent recurrence, row-group decomposed ----------------
// Batch rows are INDEPENDENT sequences: output row b needs only input row b.
// 256 WGs x 512 thr, 1 WG/CU (LDS pad). WG tile: 16 rows x 64 cols.
// rowgrp = blockIdx&7 (16 batch rows), colblk = blockIdx>>3 (64 cols).
// Sync scope = the 32 WGs of a row-group only (8 independent barriers; groups
// drift freely). 8 waves K-split 8x256; B persistent in VGPRs (128/lane).
// State via sc0sc1 write-through + uncached wide loads (IF-coherent, no fences).
__global__ __launch_bounds__(512, 1) void recur_kernel(const u16* __restrict__ res,
                                                       const u16* __restrict__ u,
                                                       u16* __restrict__ s0,
                                                       u16* __restrict__ s1,
                                                       unsigned* __restrict__ flags) {
    __shared__ float part[8][16][66];
    __shared__ char lds_pad[52000];   // force 1 WG/CU (85.8 KB > 160/2)
    const int lane = threadIdx.x & 63;
    const int w = threadIdx.x >> 6;          // K-slice 0..7
    const int rowgrp = (int)(blockIdx.x & 7);
    const int colblk = (int)(blockIdx.x >> 3);
    const int m0 = rowgrp * 16;
    const int n0 = colblk * 64;
    const int lr = lane & 15;
    const int lk = (lane >> 4) * 8;
    const int rb = (lane >> 4) * 4;
    const int kbase = w * 256;
    unsigned* myflag = flags + rowgrp * 32 + colblk;
    const unsigned* pollflag = flags + rowgrp * 32 + (lane & 31);

    if (blockIdx.x == 0xFFFFFFFFu) lds_pad[threadIdx.x] = 1;  // keep pad alive

    // persistent reservoir B-fragments: 4 col-frags x 8 K-subs = 128 VGPR/lane
    bf16x8 bfr[4][8];
#pragma unroll
    for (int jf = 0; jf < 4; jf++)
#pragma unroll
        for (int kk = 0; kk < 8; kk++)
            bfr[jf][kk] = *(const bf16x8*)(res + (size_t)(n0 + jf * 16 + lr) * RES + kbase + kk * 32 + lk);

    // epilogue mapping: thread -> (row 0..15, col pair)
    const int er = threadIdx.x >> 5;          // 0..15
    const int ec = (threadIdx.x & 31) * 2;    // 0..62
    const size_t gidx = (size_t)(m0 + er) * RES + n0 + ec;

    for (int t = 0; t < NFRAMES; t++) {
        const u16* sin = (t & 1) ? s1 : s0;
        u16* sout = (t & 1) ? s0 : s1;
        const u16* abase = sin + (size_t)(m0 + lr) * RES + kbase + lk;

        // u prefetch (immutable input, cached)
        unsigned uv = *(const unsigned*)(u + (size_t)t * BATCH * RES + gidx);

        // 8 A-loads (16 rows x 256 K slice, uncached wide), pipelined MFMA
        bf16x8 a[8];
#pragma unroll
        for (int kk = 0; kk < 8; kk++)
            asm volatile("global_load_dwordx4 %0, %1, off sc0 sc1"
                         : "=v"(a[kk]) : "v"(abase + kk * 32));

        f32x4 acc[4];
#pragma unroll
        for (int jf = 0; jf < 4; jf++) acc[jf] = (f32x4)0.f;

        asm volatile("s_waitcnt vmcnt(4)" ::: "memory");
        __builtin_amdgcn_sched_barrier(0);
#pragma unroll
        for (int kk = 0; kk < 4; kk++)
#pragma unroll
            for (int jf = 0; jf < 4; jf++)
                acc[jf] = __builtin_amdgcn_mfma_f32_16x16x32_bf16(a[kk], bfr[jf][kk], acc[jf], 0, 0, 0);
        asm volatile("s_waitcnt vmcnt(0)" ::: "memory");
        __builtin_amdgcn_sched_barrier(0);
#pragma unroll
        for (int kk = 4; kk < 8; kk++)
#pragma unroll
            for (int jf = 0; jf < 4; jf++)
                acc[jf] = __builtin_amdgcn_mfma_f32_16x16x32_bf16(a[kk], bfr[jf][kk], acc[jf], 0, 0, 0);

        // K-partials -> LDS (stride 66: 8B-aligned float2 reads, ~2-4 way banks)
#pragma unroll
        for (int jf = 0; jf < 4; jf++)
#pragma unroll
            for (int q = 0; q < 4; q++)
                part[w][rb + q][jf * 16 + lr] = acc[jf][q];
        __syncthreads();

        // reduce 8 K-partials + u add + fast tanh + packed write-through store
        float sx = 0.f, sy = 0.f;
#pragma unroll
        for (int ww = 0; ww < 8; ww++) {
            float2 v = *(const float2*)&part[ww][er][ec];
            sx += v.x; sy += v.y;
        }
        float v0 = tanh_fast(sx + bf2f((u16)(uv & 0xFFFF)));
        float v1 = tanh_fast(sy + bf2f((u16)(uv >> 16)));
        unsigned pk = (unsigned)f2bf(v0) | ((unsigned)f2bf(v1) << 16);
        asm volatile("global_store_dword %0, %1, off sc0 sc1"
                     :: "v"(sout + gidx), "v"(pk) : "memory");

        // drain own stores + loads, then ROW-GROUP barrier (32 WGs only):
        // own-slot stamp store + one 64-lane poll over the group's 32 flags.
        asm volatile("s_waitcnt vmcnt(0)" ::: "memory");
        __syncthreads();
        if (t != NFRAMES - 1) {
            unsigned stamp = (unsigned)(t + 1);
            if (w == 0) {
                if (lane == 0)
                    asm volatile("global_store_dword %0, %1, off sc0 sc1"
                                 :: "v"(myflag), "v"(stamp) : "memory");
                unsigned f;
                do {
                    asm volatile("global_load_dword %0, %1, off sc0 sc1\n\ts_waitcnt vmcnt(0)"
                                 : "=v"(f) : "v"(pollflag) : "memory");
                    if (__all((int)(f >= stamp))) break;
                    __builtin_amdgcn_s_sleep(2);
                } while (1);
            }
            __syncthreads();
        }
    }
}

// ---------------- head: logits[b,c] = sum_r s[b,r]*W_out[c,r] + bias[c] ----------------
__global__ __launch_bounds__(512) void head_kernel(const u16* __restrict__ sin,
                                                   const u16* __restrict__ wout,
                                                   const float* __restrict__ bias,
                                                   float* __restrict__ out) {
    __shared__ float part[8][32][33];
    int lane = threadIdx.x & 63;
    int w = threadIdx.x >> 6;
    int m0 = blockIdx.x * 32;
    int n0 = blockIdx.y * 32;   // over padded 1024
    int k0 = w * 256;
    int lr = lane & 15;
    int lk = (lane >> 4) * 8;

    f32x4 acc[2][2];
#pragma unroll
    for (int i = 0; i < 2; i++)
#pragma unroll
        for (int j = 0; j < 2; j++) acc[i][j] = (f32x4)0.f;

    for (int kk = k0; kk < k0 + 256; kk += 32) {
        bf16x8 a[2], b[2];
#pragma unroll
        for (int i = 0; i < 2; i++)
            a[i] = *(const bf16x8*)(sin + (size_t)(m0 + i * 16 + lr) * RES + kk + lk);
#pragma unroll
        for (int j = 0; j < 2; j++) {
            int row = n0 + j * 16 + lr;
            if (row > NCLS - 1) row = NCLS - 1;  // clamp, result unused
            b[j] = *(const bf16x8*)(wout + (size_t)row * RES + kk + lk);
        }
#pragma unroll
        for (int i = 0; i < 2; i++)
#pragma unroll
            for (int j = 0; j < 2; j++)
                acc[i][j] = __builtin_amdgcn_mfma_f32_16x16x32_bf16(a[i], b[j], acc[i][j], 0, 0, 0);
    }

    int rowbase = (lane >> 4) * 4;
#pragma unroll
    for (int i = 0; i < 2; i++)
#pragma unroll
        for (int j = 0; j < 2; j++)
#pragma unroll
            for (int q = 0; q < 4; q++)
                part[w][i * 16 + rowbase + q][j * 16 + lr] = acc[i][j][q];

    __syncthreads();

    for (int idx = threadIdx.x; idx < 1024; idx += 512) {
        int r = idx >> 5, c = idx & 31;
        float s = 0.f;
#pragma unroll
        for (int ww = 0; ww < 8; ww++) s += part[ww][r][c];
        int cg = n0 + c;
        if (cg < NCLS)
            out[(size_t)(m0 + r) * NCLS + cg] = s + bias[cg];
    }
}

extern "C" void kernel_launch(void* const* d_in, const int* in_sizes, int n_in,
                              void* d_out, int out_size, void* d_ws, size_t ws_size,
                              hipStream_t stream) {
    const float* x_f    = (const float*)d_in[0];  // [128,256,768]
    const float* res_f  = (const float*)d_in[1];  // [2048,2048]
    const float* win_f  = (const float*)d_in[2];  // [2048,768]
    const float* wout_f = (const float*)d_in[3];  // [1000,2048]
    const float* bias   = (const float*)d_in[4];  // [1000]
    float* out = (float*)d_out;

    char* ws = (char*)d_ws;
    size_t off = 0;
    auto alloc = [&](size_t bytes) -> void* {
        void* p = ws + off;
        off += (bytes + 255) & ~(size_t)255;
        return p;
    };
    u16* res_b  = (u16*)alloc((size_t)RES * RES * 2);
    u16* win_b  = (u16*)alloc((size_t)RES * EMBED * 2);
    u16* wout_b = (u16*)alloc((size_t)NCLS * RES * 2);
    u16* x_b    = (u16*)alloc((size_t)BATCH * NFRAMES * EMBED * 2);
    u16* u      = (u16*)alloc((size_t)NFRAMES * BATCH * RES * 2);
    u16* s0     = (u16*)alloc((size_t)BATCH * RES * 2);
    u16* s1     = (u16*)alloc((size_t)BATCH * RES * 2);
    unsigned* flags = (unsigned*)alloc(1024);

    // weight / input conversion to bf16
    cvt_kernel<<<dim3(1024), dim3(256), 0, stream>>>(res_f, res_b, RES * RES / 4);
    cvt_kernel<<<dim3(512), dim3(256), 0, stream>>>(win_f, win_b, RES * EMBED / 4);
    cvt_kernel<<<dim3(512), dim3(256), 0, stream>>>(wout_f, wout_b, NCLS * RES / 4);
    cvt_kernel<<<dim3(2048), dim3(256), 0, stream>>>(x_f, x_b, BATCH * NFRAMES * EMBED / 4);

    // state0 = 0, flags = 0 (ws poisoned 0xAA; re-init every call)
    hipMemsetAsync(s0, 0, (size_t)BATCH * RES * 2, stream);
    hipMemsetAsync(flags, 0, 1024, stream);

    // u[t,b,r] projection GEMM
    proj_kernel<<<dim3(256, 16), dim3(256), 0, stream>>>(x_b, win_b, u);

    // all 256 recurrence steps in one cooperative launch
    void* args[] = { (void*)&res_b, (void*)&u, (void*)&s0, (void*)&s1, (void*)&flags };
    hipLaunchCooperativeKernel((const void*)recur_kernel, dim3(NWG), dim3(512),
                               args, 0, stream);

    // final state is in s0 (t=255 odd -> wrote s0)
    head_kernel<<<dim3(4, 32), dim3(512), 0, stream>>>(s0, wout_b, bias, out);
}